// Round 1
// baseline (239.711 us; speedup 1.0000x reference)
//
#include <hip/hip_runtime.h>

#define DIM 2048

// XOR-swizzle LDS addresses: bits 2..4 ^= bits 7..9. Keeps 16B chunks
// contiguous (only touches bits >=2) and makes every transpose phase
// bank-uniform (8 dwords/bank, conflict-free).
__device__ __forceinline__ int sw(int e) {
  return e ^ (((e >> 7) & 7) << 2);
}

// Exact sign flip: signs are +/-1 int32; -1 has the int sign bit set.
__device__ __forceinline__ float4 sign_flip(float4 v, uint4 s) {
  float4 r;
  r.x = __uint_as_float(__float_as_uint(v.x) ^ (s.x & 0x80000000u));
  r.y = __uint_as_float(__float_as_uint(v.y) ^ (s.y & 0x80000000u));
  r.z = __uint_as_float(__float_as_uint(v.z) ^ (s.z & 0x80000000u));
  r.w = __uint_as_float(__float_as_uint(v.w) ^ (s.w & 0x80000000u));
  return r;
}

#define BFLY(a, b) { float _t = (a); (a) = _t + (b); (b) = _t - (b); }

__device__ __forceinline__ void bf4_pair(float4 &a, float4 &b) {
  BFLY(a.x, b.x); BFLY(a.y, b.y); BFLY(a.z, b.z); BFLY(a.w, b.w);
}

// Butterfly element-index bits 0 and 1 (within the float4 components).
__device__ __forceinline__ void bf_comps(float4 &a) {
  BFLY(a.x, a.y); BFLY(a.z, a.w);   // bit 0
  BFLY(a.x, a.z); BFLY(a.y, a.w);   // bit 1
}

// Butterfly the 3 bits of the 8-register index (strides 1,2,4).
__device__ __forceinline__ void bf_oct(float4 v[8]) {
  bf4_pair(v[0], v[1]); bf4_pair(v[2], v[3]);
  bf4_pair(v[4], v[5]); bf4_pair(v[6], v[7]);
  bf4_pair(v[0], v[2]); bf4_pair(v[1], v[3]);
  bf4_pair(v[4], v[6]); bf4_pair(v[5], v[7]);
  bf4_pair(v[0], v[4]); bf4_pair(v[1], v[5]);
  bf4_pair(v[2], v[6]); bf4_pair(v[3], v[7]);
}

// Cross-lane butterfly on lane bit 0 / 1 via DPP quad_perm (VALU rate,
// no DS-pipe traffic). 0xB1 = [1,0,3,2] (xor1), 0x4E = [2,3,0,1] (xor2).
template <int CTRL>
__device__ __forceinline__ float dpp_mov(float x) {
  return __int_as_float(
      __builtin_amdgcn_mov_dpp(__float_as_int(x), CTRL, 0xF, 0xF, true));
}

template <int CTRL>
__device__ __forceinline__ void dpp_stage(float4 v[8], float sgn) {
  #pragma unroll
  for (int i = 0; i < 8; ++i) {
    float px = dpp_mov<CTRL>(v[i].x);
    float py = dpp_mov<CTRL>(v[i].y);
    float pz = dpp_mov<CTRL>(v[i].z);
    float pw = dpp_mov<CTRL>(v[i].w);
    // lane with bit clear: x + partner ; lane with bit set: partner - x
    v[i].x = fmaf(sgn, v[i].x, px);
    v[i].y = fmaf(sgn, v[i].y, py);
    v[i].z = fmaf(sgn, v[i].z, pz);
    v[i].w = fmaf(sgn, v[i].w, pw);
  }
}

// One wave per 2048-float row. 32 floats/lane in registers.
// Layout1 (load):  e = c*256 + lane*4 + r        (comps=bits0-1, c=bits8-10, lane=bits2-7)
// Layout2 (after transpose 1): e = r + 4*l1 + 8*l2 + 16*j + 128*l0 + 256*(lane>>3)
// Layout3 (after transpose 2): e = r + 4*l1 + 8*l0 + 16*l2 + 32*l3 + 64*l4 + 128*l5 + 256*c
__global__ __launch_bounds__(256) void srht2_kernel(
    const float* __restrict__ x, const int* __restrict__ signs,
    float* __restrict__ out, int nrows) {
  __shared__ __align__(16) float lds[4][DIM];
  const int lane = threadIdx.x & 63;
  const int wv   = threadIdx.x >> 6;
  const int row  = blockIdx.x * 4 + wv;

  const float sgn1 = (lane & 1) ? -1.0f : 1.0f;
  const float sgn2 = (lane & 2) ? -1.0f : 1.0f;

  const float4* __restrict__ xr = (const float4*)(x + (size_t)row * DIM);
  const uint4*  __restrict__ s0 = (const uint4*)signs;

  float4 v[8];
  #pragma unroll
  for (int c = 0; c < 8; ++c) v[c] = xr[c * 64 + lane];
  #pragma unroll
  for (int c = 0; c < 8; ++c) v[c] = sign_flip(v[c], s0[c * 64 + lane]);

  // ---- pass 1, pre-transpose: bits 0,1 (comps), 8,9,10 (c), 2,3 (DPP) ----
  #pragma unroll
  for (int c = 0; c < 8; ++c) bf_comps(v[c]);
  bf_oct(v);
  dpp_stage<0xB1>(v, sgn1);   // bit 2 (lane bit 0)
  dpp_stage<0x4E>(v, sgn2);   // bit 3 (lane bit 1)

  // ---- transpose 1 (per-wave LDS slice, swizzled, b128 both ways) ----
  float* L = lds[wv];
  #pragma unroll
  for (int c = 0; c < 8; ++c)
    *(float4*)(L + sw(c * 256 + lane * 4)) = v[c];
  __syncthreads();

  const int rbase = (((lane >> 1) & 1) << 2) | (((lane >> 2) & 1) << 3)
                  | ((lane & 1) << 7) | ((lane >> 3) << 8);
  float4 w[8];
  #pragma unroll
  for (int j = 0; j < 8; ++j)
    w[j] = *(const float4*)(L + sw(rbase + (j << 4)));

  // ---- pass 1, post-transpose: bits 4,5,6 (j), 7 (DPP) ----
  bf_oct(w);
  dpp_stage<0xB1>(w, sgn1);   // bit 7 (lane bit 0 in layout2)

  // ---- pass 2: sign flip (layout2 addressing into signs[1]) ----
  const uint4* __restrict__ s1 = (const uint4*)(signs + DIM);
  #pragma unroll
  for (int j = 0; j < 8; ++j)
    w[j] = sign_flip(w[j], s1[(rbase >> 2) + (j << 2)]);

  // ---- pass 2, pre-transpose: bits 0,1 (comps), 4,5,6 (j), 7,2 (DPP) ----
  #pragma unroll
  for (int j = 0; j < 8; ++j) bf_comps(w[j]);
  bf_oct(w);
  dpp_stage<0xB1>(w, sgn1);   // bit 7 (lane bit 0)
  dpp_stage<0x4E>(w, sgn2);   // bit 2 (lane bit 1)

  // ---- transpose 2 ----
  __syncthreads();
  #pragma unroll
  for (int j = 0; j < 8; ++j)
    *(float4*)(L + sw(rbase + (j << 4))) = w[j];
  __syncthreads();

  const int rb2 = ((lane & 1) << 3) | (((lane >> 1) & 1) << 2)
                | (((lane >> 2) & 1) << 4) | (((lane >> 3) & 1) << 5)
                | (((lane >> 4) & 1) << 6) | (((lane >> 5) & 1) << 7);
  #pragma unroll
  for (int c = 0; c < 8; ++c)
    v[c] = *(const float4*)(L + sw(rb2 + (c << 8)));

  // ---- pass 2, post-transpose: bits 8,9,10 (c), 3 (DPP) ----
  bf_oct(v);
  dpp_stage<0xB1>(v, sgn1);   // bit 3 (lane bit 0 in layout3)

  // ---- scale (exact pow2) and coalesced store ----
  const float sc = 1.0f / 2048.0f;
  float4* __restrict__ orow = (float4*)(out + (size_t)row * DIM);
  #pragma unroll
  for (int c = 0; c < 8; ++c) {
    float4 t = v[c];
    t.x *= sc; t.y *= sc; t.z *= sc; t.w *= sc;
    orow[(rb2 >> 2) + (c << 6)] = t;
  }
}

extern "C" void kernel_launch(void* const* d_in, const int* in_sizes, int n_in,
                              void* d_out, int out_size, void* d_ws, size_t ws_size,
                              hipStream_t stream) {
  const float* x     = (const float*)d_in[0];
  const int*   signs = (const int*)d_in[1];
  float*       out   = (float*)d_out;
  const int nrows   = in_sizes[0] / DIM;   // 16384
  const int nblocks = nrows / 4;           // 4 waves (rows) per block
  hipLaunchKernelGGL(srht2_kernel, dim3(nblocks), dim3(256), 0, stream,
                     x, signs, out, nrows);
}